// Round 1
// baseline (195.160 us; speedup 1.0000x reference)
//
#include <hip/hip_runtime.h>
#include <math.h>

#define BB 4
#define HH 512
#define WW 512
#define HWSZ (HH * WW)

// ws layout:
//   [0,   16)      int present[4]            (zeroed via hipMemsetAsync)
//   [64,  64+16KB) double partials[BB*HH]    (fully written by edt_rows)
//   [32768, +4MB)  u32 gpack[BB*HH*WW]       (low16 = g for seed=mask, high16 = g for seed=~mask)

// ---------------------------------------------------------------------------
// Pass 1: per-column 1D nearest-seed distance for BOTH seeds (mask, ~mask).
// One thread per (batch, column). Forward scan writes fwd distances (packed),
// backward scan combines with bwd distances -> final g (packed u16, 0xFFFF =
// "no seed" sentinel). Also counts mask pixels per batch (presence guard).
// ---------------------------------------------------------------------------
__global__ __launch_bounds__(256) void edt_cols_kernel(
    const int* __restrict__ target,
    unsigned int* __restrict__ gpack,
    int* __restrict__ present)
{
    int col = blockIdx.x * 256 + threadIdx.x;   // 0 .. BB*WW-1
    int b = col >> 9;                           // / WW
    int j = col & (WW - 1);
    const int* t = target + b * HWSZ + j;
    unsigned int* gp = gpack + b * HWSZ + j;

    int lastN = -1, lastP = -1;                 // last seed row seen (N: mask, P: ~mask)
    int cnt = 0;
    for (int i = 0; i < HH; ++i) {
        int m = (t[i * WW] == 1);
        cnt += m;
        if (m) lastN = i; else lastP = i;
        unsigned int dN = (lastN >= 0) ? (unsigned int)(i - lastN) : 0xFFFFu;
        unsigned int dP = (lastP >= 0) ? (unsigned int)(i - lastP) : 0xFFFFu;
        gp[i * WW] = dN | (dP << 16);
    }
    int nxtN = -1, nxtP = -1;                   // next seed row at/below i
    for (int i = HH - 1; i >= 0; --i) {
        unsigned int pk = gp[i * WW];
        unsigned int fN = pk & 0xFFFFu;
        unsigned int fP = pk >> 16;
        if (fN == 0u) nxtN = i;                 // fwd distance 0 <=> seed at i
        if (fP == 0u) nxtP = i;
        unsigned int bN = (nxtN >= 0) ? (unsigned int)(nxtN - i) : 0xFFFFu;
        unsigned int bP = (nxtP >= 0) ? (unsigned int)(nxtP - i) : 0xFFFFu;
        unsigned int gN = fN < bN ? fN : bN;
        unsigned int gP = fP < bP ? fP : bP;
        gp[i * WW] = gN | (gP << 16);
    }
    atomicAdd(&present[b], cnt);
}

// ---------------------------------------------------------------------------
// Pass 2: exact row lower-envelope  d2(j) = min_k g2[k] + (j-k)^2  for both
// maps, via expanding-ring search with early exit (exact: (j-k)^2 is monotone
// in the radius, so once r^2 >= both current bests no further k can improve).
// All quantities are exact small integers in fp32 -> bit-identical to the
// reference's fp32 min. Then dmap = sqrt(d2n) - sqrt(d2p), weighted by
// p1 = sigmoid(pred1 - pred0), accumulated in double, one partial per block.
// ---------------------------------------------------------------------------
__global__ __launch_bounds__(256) void edt_rows_kernel(
    const unsigned int* __restrict__ gpack,
    const float* __restrict__ pred,
    const int* __restrict__ present,
    double* __restrict__ partials)
{
    __shared__ float g2n[WW];
    __shared__ float g2p[WW];
    __shared__ double red[256];

    int bi = blockIdx.x;            // 0 .. BB*HH-1
    int b = bi >> 9;                // / HH
    int i = bi & (HH - 1);
    int tid = threadIdx.x;

    const unsigned int* gp = gpack + b * HWSZ + i * WW;
    for (int k = tid; k < WW; k += 256) {
        unsigned int pk = gp[k];
        unsigned int gN = pk & 0xFFFFu;
        unsigned int gP = pk >> 16;
        g2n[k] = (gN == 0xFFFFu) ? 1e18f : (float)(gN * gN);
        g2p[k] = (gP == 0xFFFFu) ? 1e18f : (float)(gP * gP);
    }
    __syncthreads();

    const float* p0 = pred + (b * 2 + 0) * HWSZ + i * WW;
    const float* p1 = pred + (b * 2 + 1) * HWSZ + i * WW;

    double local = 0.0;
    for (int j = tid; j < WW; j += 256) {
        float bn = g2n[j];          // r = 0 candidate
        float bp = g2p[j];
        for (int r = 1; r < WW; ++r) {
            float sq = (float)(r * r);
            if (sq >= bn && sq >= bp) break;   // no farther k can improve
            int kl = j - r;
            int kr = j + r;
            if (kl >= 0) {
                bn = fminf(bn, sq + g2n[kl]);
                bp = fminf(bp, sq + g2p[kl]);
            }
            if (kr < WW) {
                bn = fminf(bn, sq + g2n[kr]);
                bp = fminf(bp, sq + g2p[kr]);
            }
        }
        float dist = sqrtf(bn) - sqrtf(bp);    // negEDT - posEDT
        float x0 = p0[j];
        float x1 = p1[j];
        float prob = 1.0f / (1.0f + expf(x0 - x1));   // softmax class-1
        local += (double)(prob * dist);
    }

    red[tid] = local;
    __syncthreads();
    for (int off = 128; off > 0; off >>= 1) {
        if (tid < off) red[tid] += red[tid + off];
        __syncthreads();
    }
    if (tid == 0) {
        double scale = (present[b] > 0) ? 1.0 : 0.0;  // 'if mask.sum() > 0' guard
        partials[bi] = red[0] * scale;
    }
}

__global__ __launch_bounds__(256) void finalize_kernel(
    const double* __restrict__ partials, float* __restrict__ out)
{
    __shared__ double red[256];
    int tid = threadIdx.x;
    double s = 0.0;
    for (int idx = tid; idx < BB * HH; idx += 256) s += partials[idx];
    red[tid] = s;
    __syncthreads();
    for (int off = 128; off > 0; off >>= 1) {
        if (tid < off) red[tid] += red[tid + off];
        __syncthreads();
    }
    if (tid == 0) {
        // mean over B*C*H*W = 4*2*512*512 (class-0 map contributes zero)
        out[0] = (float)(red[0] * (1.0 / 2097152.0));
    }
}

extern "C" void kernel_launch(void* const* d_in, const int* in_sizes, int n_in,
                              void* d_out, int out_size, void* d_ws, size_t ws_size,
                              hipStream_t stream) {
    const float* pred = (const float*)d_in[0];
    const int* target = (const int*)d_in[1];
    float* out = (float*)d_out;

    char* ws = (char*)d_ws;
    int* present = (int*)(ws + 0);
    double* partials = (double*)(ws + 64);
    unsigned int* gpack = (unsigned int*)(ws + 32768);

    hipMemsetAsync(present, 0, 64, stream);

    edt_cols_kernel<<<(BB * WW) / 256, 256, 0, stream>>>(target, gpack, present);
    edt_rows_kernel<<<BB * HH, 256, 0, stream>>>(gpack, pred, present, partials);
    finalize_kernel<<<1, 256, 0, stream>>>(partials, out);
}

// Round 2
// 76.020 us; speedup vs baseline: 2.5672x; 2.5672x over previous
//
#include <hip/hip_runtime.h>
#include <math.h>

#define BB 4
#define HH 512
#define WW 512
#define HWSZ (HH * WW)

#define TCOLS 16    // columns per block
#define TCH   16    // row-chunks per block
#define CROWS 32    // rows per chunk (TCH*CROWS == HH)

// ws layout:
//   [0,    512)    int counts[128]        (one per edt_cols block; all written)
//   [1024, +16KB)  double partials[2048]  (one per edt_rows block; all written)
//   [32768, +4MB)  u32 gpack[BB*HH*WW]    (low16 = g seed=mask, high16 = g seed=~mask)

// ---------------------------------------------------------------------------
// Pass 1: per-column 1D nearest-seed distances for BOTH seeds via a
// block-level segmented scan. Thread (c, ch) owns 32 rows of one column,
// packs the mask into a u32 bitfield; chunk summaries (first/last seed row)
// go to LDS; a 16-step LDS scan yields per-chunk boundary prefixes; final
// per-row distances come from clz/ctz on the register bitmask (no serial
// dependency, 32 independent unrolled loads per thread for deep ILP).
// ---------------------------------------------------------------------------
__global__ __launch_bounds__(256) void edt_cols_kernel(
    const int* __restrict__ target,
    unsigned int* __restrict__ gpack,
    int* __restrict__ counts)
{
    int blk = blockIdx.x;          // b*32 + tile
    int b = blk >> 5;
    int tile = blk & 31;
    int tid = threadIdx.x;
    int c = tid & (TCOLS - 1);     // column within tile
    int ch = tid >> 4;             // chunk index
    int j = tile * TCOLS + c;
    int r0 = ch * CROWS;

    const int* t = target + b * HWSZ + j;

    // 32 independent loads -> one 32-bit row mask
    unsigned int maskN = 0;
#pragma unroll
    for (int i = 0; i < CROWS; ++i)
        maskN |= (unsigned int)(t[(r0 + i) * WW] == 1) << i;
    unsigned int maskP = ~maskN;

    __shared__ short sLastN[TCH][TCOLS], sLastP[TCH][TCOLS];
    __shared__ short sFirstN[TCH][TCOLS], sFirstP[TCH][TCOLS];
    __shared__ short sBefN[TCH][TCOLS], sBefP[TCH][TCOLS];
    __shared__ short sAftN[TCH][TCOLS], sAftP[TCH][TCOLS];
    __shared__ int sCnt;

    sLastN[ch][c]  = maskN ? (short)(r0 + 31 - __builtin_clz(maskN)) : (short)-1;
    sFirstN[ch][c] = maskN ? (short)(r0 + __builtin_ctz(maskN))      : (short)-1;
    sLastP[ch][c]  = maskP ? (short)(r0 + 31 - __builtin_clz(maskP)) : (short)-1;
    sFirstP[ch][c] = maskP ? (short)(r0 + __builtin_ctz(maskP))      : (short)-1;
    if (tid == 0) sCnt = 0;
    __syncthreads();

    if (tid < TCOLS) {             // one thread per column: 16-step chunk scan
        short befN = -1, befP = -1;
        for (int k = 0; k < TCH; ++k) {
            sBefN[k][tid] = befN; sBefP[k][tid] = befP;
            short ln = sLastN[k][tid], lp = sLastP[k][tid];
            if (ln >= 0) befN = ln;
            if (lp >= 0) befP = lp;
        }
        short aftN = -1, aftP = -1;
        for (int k = TCH - 1; k >= 0; --k) {
            sAftN[k][tid] = aftN; sAftP[k][tid] = aftP;
            short fn = sFirstN[k][tid], fp = sFirstP[k][tid];
            if (fn >= 0) aftN = fn;
            if (fp >= 0) aftP = fp;
        }
    }
    atomicAdd(&sCnt, __popc(maskN));
    __syncthreads();

    int befN = sBefN[ch][c], befP = sBefP[ch][c];
    int aftN = sAftN[ch][c], aftP = sAftP[ch][c];
    unsigned int* gp = gpack + b * HWSZ + j;

#pragma unroll
    for (int i = 0; i < CROWS; ++i) {
        int row = r0 + i;
        unsigned int belowN = maskN << (31 - i);   // bit31 = row i
        unsigned int aboveN = maskN >> i;          // bit0  = row i
        unsigned int dfN = belowN ? (unsigned int)__builtin_clz(belowN)
                                  : (befN >= 0 ? (unsigned int)(row - befN) : 0xFFFFu);
        unsigned int dbN = aboveN ? (unsigned int)__builtin_ctz(aboveN)
                                  : (aftN >= 0 ? (unsigned int)(aftN - row) : 0xFFFFu);
        unsigned int gN = dfN < dbN ? dfN : dbN;

        unsigned int belowP = maskP << (31 - i);
        unsigned int aboveP = maskP >> i;
        unsigned int dfP = belowP ? (unsigned int)__builtin_clz(belowP)
                                  : (befP >= 0 ? (unsigned int)(row - befP) : 0xFFFFu);
        unsigned int dbP = aboveP ? (unsigned int)__builtin_ctz(aboveP)
                                  : (aftP >= 0 ? (unsigned int)(aftP - row) : 0xFFFFu);
        unsigned int gP = dfP < dbP ? dfP : dbP;

        gp[row * WW] = gN | (gP << 16);
    }

    if (tid == 0) counts[blk] = sCnt;
}

// ---------------------------------------------------------------------------
// Pass 2: exact row lower-envelope  d2(j) = min_k g2[k] + (j-k)^2  for both
// maps via expanding-ring search with early exit (exact: once r^2 >= both
// current bests no farther k can improve). All quantities exact integers in
// fp32 -> bit-identical to the reference. dmap = sqrt(d2n) - sqrt(d2p),
// weighted by p1 = sigmoid(pred1 - pred0), double accumulation, one partial
// per block (guard applied in finalize).
// ---------------------------------------------------------------------------
__global__ __launch_bounds__(256) void edt_rows_kernel(
    const unsigned int* __restrict__ gpack,
    const float* __restrict__ pred,
    double* __restrict__ partials)
{
    __shared__ float g2n[WW];
    __shared__ float g2p[WW];
    __shared__ double red[256];

    int bi = blockIdx.x;            // b*HH + i
    int b = bi >> 9;
    int i = bi & (HH - 1);
    int tid = threadIdx.x;

    const unsigned int* gp = gpack + b * HWSZ + i * WW;
    for (int k = tid; k < WW; k += 256) {
        unsigned int pk = gp[k];
        unsigned int gN = pk & 0xFFFFu;
        unsigned int gP = pk >> 16;
        g2n[k] = (gN == 0xFFFFu) ? 1e18f : (float)(gN * gN);
        g2p[k] = (gP == 0xFFFFu) ? 1e18f : (float)(gP * gP);
    }
    __syncthreads();

    const float* p0 = pred + (b * 2 + 0) * HWSZ + i * WW;
    const float* p1 = pred + (b * 2 + 1) * HWSZ + i * WW;

    double local = 0.0;
    for (int j = tid; j < WW; j += 256) {
        float bn = g2n[j];
        float bp = g2p[j];
        for (int r = 1; r < WW; ++r) {
            float sq = (float)(r * r);
            if (sq >= bn && sq >= bp) break;
            int kl = j - r;
            int kr = j + r;
            if (kl >= 0) {
                bn = fminf(bn, sq + g2n[kl]);
                bp = fminf(bp, sq + g2p[kl]);
            }
            if (kr < WW) {
                bn = fminf(bn, sq + g2n[kr]);
                bp = fminf(bp, sq + g2p[kr]);
            }
        }
        float dist = sqrtf(bn) - sqrtf(bp);            // negEDT - posEDT
        float prob = 1.0f / (1.0f + expf(p0[j] - p1[j]));  // softmax class-1
        local += (double)(prob * dist);
    }

    red[tid] = local;
    __syncthreads();
    for (int off = 128; off > 0; off >>= 1) {
        if (tid < off) red[tid] += red[tid + off];
        __syncthreads();
    }
    if (tid == 0) partials[bi] = red[0];
}

__global__ __launch_bounds__(256) void finalize_kernel(
    const int* __restrict__ counts,
    const double* __restrict__ partials,
    float* __restrict__ out)
{
    __shared__ int sPres[BB];
    __shared__ double red[256];
    int tid = threadIdx.x;

    if (tid < BB) sPres[tid] = 0;
    __syncthreads();
    if (tid < 128) atomicAdd(&sPres[tid >> 5], counts[tid]);  // 32 blocks/batch
    __syncthreads();

    double s = 0.0;
    for (int idx = tid; idx < BB * HH; idx += 256) {
        double g = (sPres[idx >> 9] > 0) ? 1.0 : 0.0;  // 'if mask.sum() > 0'
        s += partials[idx] * g;
    }
    red[tid] = s;
    __syncthreads();
    for (int off = 128; off > 0; off >>= 1) {
        if (tid < off) red[tid] += red[tid + off];
        __syncthreads();
    }
    if (tid == 0)
        out[0] = (float)(red[0] * (1.0 / 2097152.0));  // mean over B*C*H*W
}

extern "C" void kernel_launch(void* const* d_in, const int* in_sizes, int n_in,
                              void* d_out, int out_size, void* d_ws, size_t ws_size,
                              hipStream_t stream) {
    const float* pred = (const float*)d_in[0];
    const int* target = (const int*)d_in[1];
    float* out = (float*)d_out;

    char* ws = (char*)d_ws;
    int* counts = (int*)(ws + 0);
    double* partials = (double*)(ws + 1024);
    unsigned int* gpack = (unsigned int*)(ws + 32768);

    edt_cols_kernel<<<BB * (WW / TCOLS), 256, 0, stream>>>(target, gpack, counts);
    edt_rows_kernel<<<BB * HH, 256, 0, stream>>>(gpack, pred, partials);
    finalize_kernel<<<1, 256, 0, stream>>>(counts, partials, out);
}